// Round 14
// baseline (18.800 us; speedup 1.0000x reference)
//
#include <hip/hip_runtime.h>
#include <hip/hip_fp16.h>

#define NSTROKES 64
#define NSAMP    50
#define CANVAS   512
#define HW       (CANVAS * CANVAS)
#define TPB      1024                  // 16 waves per block (one block per row)
#define SPW      (NSTROKES / 16)       // 4 strokes per wave (stage A)
#define LSTRIDE  64                    // float2 slots per stroke list
#define NUNITS   32                    // 8 spans x 4 chunks of 16 strokes

// ---------------------------------------------------------------------------
// One block per canvas row; 16 waves. Hypothesis under test: runtime is
// MAX-bound (grid == residency capacity; barriers make block = slowest wave).
//  stage A (r13): ballot compaction into per-stroke LDS lists + 8-bit span-
//                 occupancy mask; smask[s] = (kc<<8)|mask8; scol = (r,g,b,w).
//  stage B (NEW): dynamic queue of 32 units = (span 0..7) x (chunk 0..3,
//                 16 strokes each). Waves pull units from an LDS atomic
//                 counter -> load balanced. Each unit computes the chunk's
//                 affine map (A,B) over its 64 px (2-stroke-MLP inner loop)
//                 and stores f16 to LDS. Output invariant to pull order.
//  combine: per px, compose the 4 chunk maps in stroke order (associative),
//           apply to white canvas, write out.
// ---------------------------------------------------------------------------
__global__ __launch_bounds__(TPB, 8) void raster_fused_kernel(
    const float* __restrict__ strokes,   // (64,4,2)
    const float* __restrict__ widths,    // (64,)
    const float* __restrict__ colors,    // (64,3)
    float* __restrict__ out)             // (1,3,512,512)
{
    __shared__ __align__(16) float2 slist[NSTROKES * LSTRIDE];  // 32 KB
    __shared__ unsigned int smask[NSTROKES];      // (kc<<8) | 8-bit span mask
    __shared__ float4       scol [NSTROKES];      // r,g,b,w
    __shared__ __half2      hmap [NUNITS][64][2]; // unit maps: (A,Br),(Bg,Bb) 16 KB
    __shared__ int          uctr;

    const int tid  = threadIdx.x;
    const int wave = tid >> 6;
    const int lane = tid & 63;
    const int y    = blockIdx.x;
    const float fy = (float)y;

    if (tid == 0) uctr = 0;

    // ---- stage A: compaction + span-mask, SPW strokes per wave (r13)
    #pragma unroll
    for (int i = 0; i < SPW; ++i) {
        const int s = wave * SPW + i;        // stroke id 0..63

        float4 a = ((const float4*)strokes)[s * 2];       // p0x,p0y,p1x,p1y
        float4 b = ((const float4*)strokes)[s * 2 + 1];   // p2x,p2y,p3x,p3y
        const float S = (float)CANVAS;
        float c0x = a.x * S;
        float c1x = 3.0f * (a.z - a.x) * S;
        float c2x = 3.0f * (b.x - 2.0f * a.z + a.x) * S;
        float c3x = (b.z - 3.0f * b.x + 3.0f * a.z - a.x) * S;
        float c0y = a.y * S;
        float c1y = 3.0f * (a.w - a.y) * S;
        float c2y = 3.0f * (b.y - 2.0f * a.w + a.y) * S;
        float c3y = (b.w - 3.0f * b.y + 3.0f * a.w - a.y) * S;

        float w   = widths[s];
        float cut = w + 10.0f;               // alpha <= sigmoid(-20) ~ 2e-9 beyond

        float t   = (float)lane * (1.0f / (float)(NSAMP - 1));
        float px_ = fmaf(fmaf(fmaf(c3x, t, c2x), t, c1x), t, c0x);
        float py_ = fmaf(fmaf(fmaf(c3y, t, c2y), t, c1y), t, c0y);

        bool keep = (lane < NSAMP) && (fabsf(py_ - fy) <= cut);
        unsigned long long kmask = __ballot(keep);
        int idx = __popcll(kmask & ((1ull << lane) - 1ull));
        if (keep) {
            slist[s * LSTRIDE + idx] = make_float2(px_, py_);
        } else if (lane >= NSAMP) {
            // lanes 50..63: idx == kc for all -> consecutive sentinel slots
            slist[s * LSTRIDE + idx + (lane - NSAMP)] = make_float2(1e15f, 1e15f);
        }

        const int k0 = ((int)fmaxf(px_ - cut, 0.0f))   >> 6;
        const int k1 = ((int)fminf(px_ + cut, 511.0f)) >> 6;
        unsigned int mb = 0u;
        #pragma unroll
        for (int bb = 0; bb < 8; ++bb)
            mb |= (__ballot(keep && (k0 <= bb) && (bb <= k1)) != 0ull)
                      ? (1u << bb) : 0u;

        if (lane == 0) {
            smask[s] = ((unsigned int)__popcll(kmask) << 8) | mb;
            scol [s] = make_float4(colors[3*s], colors[3*s+1],
                                   colors[3*s+2], w);
        }
    }
    __syncthreads();

    // ---- stage B: dynamic unit queue. unit u: span=u&7, chunk=u>>3,
    //      strokes chunk*16..chunk*16+15, pixels span*64..span*64+63.
    for (;;) {
        int u = 0;
        if (lane == 0) u = atomicAdd(&uctr, 1);
        u = __shfl(u, 0);
        if (u >= NUNITS) break;

        const int span  = u & 7;
        const int sb    = (u >> 3) << 4;          // first stroke of chunk
        const float fx  = (float)((span << 6) + lane);

        // liveness of the 16 chunk strokes on this span (bits replicate x4)
        const unsigned int hdr_l = smask[sb + (lane & 15)];
        unsigned int live = (unsigned int)__ballot((hdr_l >> span) & 1u) & 0xFFFFu;

        float A = 1.0f, br = 0.0f, bg = 0.0f, bb = 0.0f;

        while (live) {
            const int s0 = sb + (__ffs(live) - 1);
            live &= live - 1u;
            const bool has1 = (live != 0u);
            const int s1 = has1 ? (sb + (__ffs(live) - 1)) : s0;
            if (has1) live &= live - 1u;

            const unsigned int h0 = smask[s0];
            const unsigned int h1 = smask[s1];
            float4 col0 = scol[s0];
            float4 col1 = scol[s1];
            const int   kc0 = (int)(h0 >> 8);
            const int   kc1 = has1 ? (int)(h1 >> 8) : 0;
            const float w0  = col0.w;
            const float w1  = col1.w;

            float m0 = 1e30f, m1 = 1e30f;
            const float4* L0 = (const float4*)(slist + s0 * LSTRIDE);
            const float4* L1 = (const float4*)(slist + s1 * LSTRIDE);

            const int kmax = kc0 > kc1 ? kc0 : kc1;
            for (int j = 0; j < kmax; j += 4) {        // sentinel-padded to 4
                if (j < kc0) {                          // wave-uniform branch
                    float4 q0 = L0[(j >> 1)];
                    float4 q1 = L0[(j >> 1) + 1];
                    float dy0 = fy - q0.y, dy1 = fy - q0.w;
                    float dy2 = fy - q1.y, dy3 = fy - q1.w;
                    float d0  = fx - q0.x, d1  = fx - q0.z;
                    float d2  = fx - q1.x, d3  = fx - q1.z;
                    float a01 = fminf(fmaf(d0,d0,dy0*dy0), fmaf(d1,d1,dy1*dy1));
                    float a23 = fminf(fmaf(d2,d2,dy2*dy2), fmaf(d3,d3,dy3*dy3));
                    m0 = fminf(fminf(a01, a23), m0);
                }
                if (j < kc1) {
                    float4 q0 = L1[(j >> 1)];
                    float4 q1 = L1[(j >> 1) + 1];
                    float dy0 = fy - q0.y, dy1 = fy - q0.w;
                    float dy2 = fy - q1.y, dy3 = fy - q1.w;
                    float d0  = fx - q0.x, d1  = fx - q0.z;
                    float d2  = fx - q1.x, d3  = fx - q1.z;
                    float a01 = fminf(fmaf(d0,d0,dy0*dy0), fmaf(d1,d1,dy1*dy1));
                    float a23 = fminf(fmaf(d2,d2,dy2*dy2), fmaf(d3,d3,dy3*dy3));
                    m1 = fminf(fminf(a01, a23), m1);
                }
            }

            float al0 = __builtin_amdgcn_rcpf(1.0f + __expf(2.0f*(sqrtf(m0)-w0)));
            float al1 = __builtin_amdgcn_rcpf(1.0f + __expf(2.0f*(sqrtf(m1)-w1)));

            A  *= (1.0f - al0);
            br  = fmaf(al0, col0.x - br, br);
            bg  = fmaf(al0, col0.y - bg, bg);
            bb  = fmaf(al0, col0.z - bb, bb);
            if (has1) {
                A  *= (1.0f - al1);
                br  = fmaf(al1, col1.x - br, br);
                bg  = fmaf(al1, col1.y - bg, bg);
                bb  = fmaf(al1, col1.z - bb, bb);
            }
        }

        hmap[u][lane][0] = __floats2half2_rn(A,  br);
        hmap[u][lane][1] = __floats2half2_rn(bg, bb);
    }
    __syncthreads();

    // ---- combine: compose 4 chunk maps in stroke order, apply to white
    if (tid < 512) {
        const int span = tid >> 6;
        const int l    = tid & 63;

        float cr = 1.0f, cg = 1.0f, cb = 1.0f;   // white canvas
        #pragma unroll
        for (int ck = 0; ck < 4; ++ck) {          // chunk 0..3 = stroke order
            const int u = (ck << 3) | span;
            float2 p0 = __half22float2(hmap[u][l][0]);   // A, Br
            float2 p1 = __half22float2(hmap[u][l][1]);   // Bg, Bb
            cr = fmaf(p0.x, cr, p0.y);
            cg = fmaf(p0.x, cg, p1.x);
            cb = fmaf(p0.x, cb, p1.y);
        }

        const int base = y * CANVAS + tid;
        out[0*HW + base] = cr;
        out[1*HW + base] = cg;
        out[2*HW + base] = cb;
    }
}

extern "C" void kernel_launch(void* const* d_in, const int* in_sizes, int n_in,
                              void* d_out, int out_size, void* d_ws, size_t ws_size,
                              hipStream_t stream) {
    const float* strokes = (const float*)d_in[0];
    const float* widths  = (const float*)d_in[1];
    const float* colors  = (const float*)d_in[2];
    float* out = (float*)d_out;

    raster_fused_kernel<<<dim3(CANVAS), dim3(TPB), 0, stream>>>(
        strokes, widths, colors, out);
}